// Round 1
// baseline (335.189 us; speedup 1.0000x reference)
//
#include <hip/hip_runtime.h>

#define Hd 128
#define LDA 136   // LDS leading dim (bf16 elems)

typedef __attribute__((ext_vector_type(8))) short short8;   // 8 bf16 = 4 VGPRs
typedef __attribute__((ext_vector_type(4))) float f32x4;

__device__ __forceinline__ unsigned short f2bf(float f) {
    union { float f; unsigned u; } v; v.f = f;
    unsigned r = v.u + 0x7FFFu + ((v.u >> 16) & 1u);   // RNE
    return (unsigned short)(r >> 16);
}

// ---------- graph prep ----------
// histogram over (rel*N + dst) buckets  (rel-major so per-tile, per-rel edges are contiguous)
__global__ __launch_bounds__(256) void count_kernel(const int* __restrict__ dst,
                                                    const int* __restrict__ et,
                                                    int* __restrict__ cnt2, int E, int N) {
    int e = blockIdx.x * 256 + threadIdx.x;
    if (e < E) atomicAdd(&cnt2[et[e] * N + dst[e]], 1);
}

// per-256-chunk sums
__global__ __launch_bounds__(256) void reduce_kernel(const int* __restrict__ cnt2,
                                                     int* __restrict__ bsum, int n) {
    __shared__ int ws[4];
    const int tid = threadIdx.x;
    int i = blockIdx.x * 256 + tid;
    int v = (i < n) ? cnt2[i] : 0;
#pragma unroll
    for (int off = 32; off > 0; off >>= 1) v += __shfl_down(v, off);
    if ((tid & 63) == 0) ws[tid >> 6] = v;
    __syncthreads();
    if (tid == 0) bsum[blockIdx.x] = ws[0] + ws[1] + ws[2] + ws[3];
}

// exclusive scan of cnt2 -> cur (each block sums its own bsum prefix); also inv2
__global__ __launch_bounds__(256) void apply_kernel(const int* __restrict__ cnt2,
                                                    const int* __restrict__ bsum,
                                                    int* __restrict__ cur,
                                                    float* __restrict__ inv2, int n) {
    __shared__ int wsum[4];
    __shared__ int bpre_s;
    const int tid = threadIdx.x;
    const int lane = tid & 63, wid = tid >> 6;
    int p = 0;
    for (int k = tid; k < blockIdx.x; k += 256) p += bsum[k];
#pragma unroll
    for (int off = 32; off > 0; off >>= 1) p += __shfl_down(p, off);
    if (lane == 0) wsum[wid] = p;
    __syncthreads();
    if (tid == 0) bpre_s = wsum[0] + wsum[1] + wsum[2] + wsum[3];
    __syncthreads();
    int i = blockIdx.x * 256 + tid;
    int x = (i < n) ? cnt2[i] : 0;
    int incl = x;
#pragma unroll
    for (int off = 1; off < 64; off <<= 1) {
        int t = __shfl_up(incl, off);
        if (lane >= off) incl += t;
    }
    __syncthreads();
    if (lane == 63) wsum[wid] = incl;
    __syncthreads();
    int wpre = 0;
    for (int k = 0; k < wid; ++k) wpre += wsum[k];
    if (i < n) {
        cur[i] = incl - x + wpre + bpre_s;
        inv2[i] = 1.0f / (float)max(x, 1);
    }
}

// counting-sort placement: epk sorted by (rel,dst), payload = src.
// post-condition: cur[b] == end offset of bucket b (start(b) = cur[b-1], cur[-1]=0)
__global__ __launch_bounds__(256) void place_kernel(const int* __restrict__ src,
                                                    const int* __restrict__ dst,
                                                    const int* __restrict__ et,
                                                    int* __restrict__ cur,
                                                    unsigned int* __restrict__ epk, int E, int N) {
    int e = blockIdx.x * 256 + threadIdx.x;
    if (e < E) {
        int pos = atomicAdd(&cur[et[e] * N + dst[e]], 1);
        epk[pos] = (unsigned int)src[e];
    }
}

// ---------- merged dtype prep: blocks 0..17 transpose weights, rest convert x ----------
__global__ __launch_bounds__(256) void cvt_prep_kernel(const float* __restrict__ x,
                                                       unsigned short* __restrict__ xbf,
                                                       int n4,
                                                       const float* __restrict__ root1,
                                                       const float* __restrict__ W1,
                                                       const float* __restrict__ root2,
                                                       const float* __restrict__ W2,
                                                       unsigned short* __restrict__ Bt) {
    const int tid = threadIdx.x;
    if (blockIdx.x < 18) {
        // Bt[b][n*128+k] = bf16(W[k*128+n]), slab-transposed (16.5 KB LDS)
        __shared__ float S[32 * 129];
        const int b = blockIdx.x;
        const float* Ws;
        if (b == 0)       Ws = root1;
        else if (b < 9)   Ws = W1 + (size_t)(b - 1) * 16384;
        else if (b == 9)  Ws = root2;
        else              Ws = W2 + (size_t)(b - 10) * 16384;
        unsigned short* Bd = Bt + (size_t)b * 16384;
        for (int s = 0; s < 4; ++s) {
            __syncthreads();
#pragma unroll
            for (int i = 0; i < 16; ++i) {     // load rows k in [32s,32s+32)
                int idx = i * 256 + tid;
                int k = idx >> 7, n = idx & 127;
                S[k * 129 + n] = Ws[(size_t)(32 * s + k) * 128 + n];
            }
            __syncthreads();
#pragma unroll
            for (int i = 0; i < 16; ++i) {     // write Bd[n][32s+kk]
                int idx = i * 256 + tid;
                int n = idx >> 5, kk = idx & 31;
                Bd[n * 128 + 32 * s + kk] = f2bf(S[kk * 129 + n]);
            }
        }
    } else {
        // grid-stride fp32 -> bf16 of x
        const int stride = (gridDim.x - 18) * 256;
        for (int i = (blockIdx.x - 18) * 256 + tid; i < n4; i += stride) {
            float4 v = ((const float4*)x)[i];
            ushort4 o;
            o.x = f2bf(v.x); o.y = f2bf(v.y); o.z = f2bf(v.z); o.w = f2bf(v.w);
            ((ushort4*)xbf)[i] = o;
        }
    }
}

// ---------- fully fused layer: per-stage A-panel is gathered (mean over bucket) in-kernel ----------
// acc = A0@Bt[0] + sum_r meangather_r(A0)@Bt[1+r]   (K_eff = 1152); no agg intermediate in HBM.
// mode 1: outb = bf16(relu(acc + bias))        mode 2: outf = relu(acc+bias).Wc + bc
__global__ __launch_bounds__(256, 2) void gemm_fused(const unsigned short* __restrict__ A0,
                                                     const int* __restrict__ cur,
                                                     const unsigned int* __restrict__ epk,
                                                     const float* __restrict__ inv2,
                                                     const unsigned short* __restrict__ Bt9,
                                                     const float* __restrict__ bias,
                                                     const float* __restrict__ Wc,
                                                     const float* __restrict__ bc,
                                                     unsigned short* __restrict__ outb,
                                                     float* __restrict__ outf,
                                                     int M, int mode) {
    __shared__ __align__(16) unsigned short As[128 * LDA];
    __shared__ __align__(16) unsigned short Bs[128 * LDA];
    const int tid = threadIdx.x;
    const int rowBase = blockIdx.x * 128;
    const int wave = tid >> 6, lane = tid & 63;
    const int lm = lane & 15, lk = (lane >> 4) * 8;
    const unsigned* x32 = (const unsigned*)A0;   // 2 bf16 per uint; gather source == A0

    f32x4 acc[2][8];
#pragma unroll
    for (int mt = 0; mt < 2; ++mt)
#pragma unroll
        for (int nt = 0; nt < 8; ++nt) acc[mt][nt] = (f32x4){0.f, 0.f, 0.f, 0.f};

    for (int t = 0; t < 9; ++t) {
        const unsigned short* Btt = Bt9 + (size_t)t * 16384;
        __syncthreads();   // previous stage's LDS reads complete
        if (t == 0) {
            // direct rows of A0 (root term) + Bs
#pragma unroll
            for (int i = 0; i < 8; ++i) {
                int idx = i * 256 + tid;
                int r = idx >> 4, c16 = idx & 15;
                int grow = rowBase + r; if (grow >= M) grow = M - 1;
                *(float4*)&As[r * LDA + c16 * 8] = *(const float4*)&A0[(size_t)grow * Hd + c16 * 8];
                *(float4*)&Bs[r * LDA + c16 * 8] = *(const float4*)&Btt[idx * 8];
            }
        } else {
            const int rr = t - 1;
            // node-bucket boundaries for this wave's 32 rows: lanes 0..32 read cur (coalesced)
            int b = 0;
            if (lane <= 32) {
                int row = rowBase + wave * 32 + lane;
                int rowc = (row < M) ? row : M;
                int gidx = rr * M + rowc - 1;
                b = (gidx < 0) ? 0 : cur[gidx];
            }
            const int begW = __builtin_amdgcn_readlane(b, 0);
            const int endW = __builtin_amdgcn_readlane(b, 32);
            float winv = 0.f;
            {
                int row = rowBase + wave * 32 + lane;
                if (lane < 32 && row < M) winv = inv2[rr * M + row];
            }
            // lane-parallel prefetch of up to 128 edge srcs (covers virtually all wave-stages)
            unsigned ep0 = 0, ep1 = 0;
            if (begW + lane < endW)      ep0 = epk[begW + lane];
            if (begW + 64 + lane < endW) ep1 = epk[begW + 64 + lane];
            // Bs fill (independent global loads; overlaps the cur->epk dependent chain)
#pragma unroll
            for (int i = 0; i < 8; ++i) {
                int idx = i * 256 + tid;
                *(float4*)&Bs[(idx >> 4) * LDA + (idx & 15) * 8] = *(const float4*)&Btt[idx * 8];
            }
            // flat edge walk, 4 outstanding row loads; flush on node-boundary crossings
            float a0 = 0.f, a1 = 0.f;
            int m = 0;
            int b_next = __builtin_amdgcn_readlane(b, 1);

#define FLUSH() { \
    float wv = __int_as_float(__builtin_amdgcn_readlane(__float_as_int(winv), m)); \
    unsigned pk = (unsigned)f2bf(a0 * wv) | ((unsigned)f2bf(a1 * wv) << 16); \
    *(unsigned*)&As[(wave * 32 + m) * LDA + lane * 2] = pk; \
    a0 = 0.f; a1 = 0.f; \
    ++m; \
    b_next = __builtin_amdgcn_readlane(b, m + 1); \
}
#define LOADV(k, vk) \
    unsigned vk = 0; \
    if (e + k < endW) { \
        int ii = e + k - begW; \
        unsigned sk = (ii < 64) ? (unsigned)__builtin_amdgcn_readlane((int)ep0, ii) \
                    : (ii < 128) ? (unsigned)__builtin_amdgcn_readlane((int)ep1, ii - 64) \
                    : epk[e + k]; \
        vk = x32[(size_t)sk * 64 + lane]; \
    }
#define CONSUME(k, vk) \
    if (e + k < endW) { \
        while (e + k >= b_next) FLUSH(); \
        a0 += __uint_as_float(vk << 16); \
        a1 += __uint_as_float(vk & 0xffff0000u); \
    }
            for (int e = begW; e < endW; e += 4) {
                LOADV(0, v0) LOADV(1, v1) LOADV(2, v2) LOADV(3, v3)
                CONSUME(0, v0) CONSUME(1, v1) CONSUME(2, v2) CONSUME(3, v3)
            }
            while (m < 32) FLUSH();   // drain: flushes in-progress node, zero rows for empties
#undef FLUSH
#undef LOADV
#undef CONSUME
        }
        __syncthreads();
#pragma unroll
        for (int ks = 0; ks < 4; ++ks) {
            const int k0 = ks * 32 + lk;
            short8 af0 = *(const short8*)&As[(wave * 32 + lm) * LDA + k0];
            short8 af1 = *(const short8*)&As[(wave * 32 + 16 + lm) * LDA + k0];
#pragma unroll
            for (int nt = 0; nt < 8; ++nt) {
                short8 bf = *(const short8*)&Bs[(nt * 16 + lm) * LDA + k0];
                acc[0][nt] = __builtin_amdgcn_mfma_f32_16x16x32_bf16(af0, bf, acc[0][nt], 0, 0, 0);
                acc[1][nt] = __builtin_amdgcn_mfma_f32_16x16x32_bf16(af1, bf, acc[1][nt], 0, 0, 0);
            }
        }
    }

    // epilogue. C/D layout: col = nt*16 + lm, row = wave*32 + mt*16 + (lane>>4)*4 + reg
    const int rquad = (lane >> 4) * 4;
    float biasr[8], wc[8];
#pragma unroll
    for (int nt = 0; nt < 8; ++nt) biasr[nt] = bias[nt * 16 + lm];
    if (mode == 2) {
#pragma unroll
        for (int nt = 0; nt < 8; ++nt) wc[nt] = Wc[nt * 16 + lm];
    }
    const float bc0 = (mode == 2) ? bc[0] : 0.f;

#pragma unroll
    for (int mt = 0; mt < 2; ++mt)
#pragma unroll
        for (int reg = 0; reg < 4; ++reg) {
            int row = rowBase + wave * 32 + mt * 16 + rquad + reg;
            if (mode == 1) {
                if (row >= M) continue;
#pragma unroll
                for (int nt = 0; nt < 8; ++nt) {
                    float v = fmaxf(acc[mt][nt][reg] + biasr[nt], 0.f);
                    outb[(size_t)row * Hd + nt * 16 + lm] = f2bf(v);
                }
            } else {
                float s = 0.f;
#pragma unroll
                for (int nt = 0; nt < 8; ++nt)
                    s += fmaxf(acc[mt][nt][reg] + biasr[nt], 0.f) * wc[nt];
                s += __shfl_xor(s, 1);
                s += __shfl_xor(s, 2);
                s += __shfl_xor(s, 4);
                s += __shfl_xor(s, 8);
                if (lm == 0 && row < M) outf[row] = s + bc0;
            }
        }
}

extern "C" void kernel_launch(void* const* d_in, const int* in_sizes, int n_in,
                              void* d_out, int out_size, void* d_ws, size_t ws_size,
                              hipStream_t stream) {
    const float* x     = (const float*)d_in[0];
    const int*   ei    = (const int*)d_in[1];
    const int*   et    = (const int*)d_in[2];
    const float* W1    = (const float*)d_in[3];
    const float* root1 = (const float*)d_in[4];
    const float* b1    = (const float*)d_in[5];
    const float* W2    = (const float*)d_in[6];
    const float* root2 = (const float*)d_in[7];
    const float* b2    = (const float*)d_in[8];
    const float* Wc    = (const float*)d_in[9];
    const float* bc    = (const float*)d_in[10];
    float* out = (float*)d_out;

    const int N = in_sizes[0] / Hd;
    const int E = in_sizes[2];
    const int* src  = ei;
    const int* dstp = ei + E;

    const size_t NH = (size_t)N * Hd;
    const int n2 = N * 8;                    // (rel,dst) bucket count
    const int nBlocks2 = (n2 + 255) / 256;

    size_t off = 0;
    auto carve = [&](size_t bytes) -> char* {
        char* p = (char*)d_ws + off;
        off += (bytes + 255) & ~(size_t)255;
        return p;
    };
    unsigned short* xbf  = (unsigned short*)carve(NH * 2);
    unsigned short* hbf  = (unsigned short*)carve(NH * 2);
    unsigned short* Bt   = (unsigned short*)carve((size_t)2 * 9 * 16384 * 2);
    int*            cnt2 = (int*)carve((size_t)n2 * 4);
    float*          inv2 = (float*)carve((size_t)n2 * 4);
    int*            cur  = (int*)carve((size_t)n2 * 4);
    int*            bsum = (int*)carve((size_t)nBlocks2 * 4);
    unsigned int*   epk  = (unsigned int*)carve((size_t)E * 4);
    if (off > ws_size) return;

    // graph prep: histogram -> inv + CSR over (rel*N+dst)
    hipMemsetAsync(cnt2, 0, (size_t)n2 * 4, stream);
    count_kernel<<<(E + 255) / 256, 256, 0, stream>>>(dstp, et, cnt2, E, N);
    reduce_kernel<<<nBlocks2, 256, 0, stream>>>(cnt2, bsum, n2);
    apply_kernel<<<nBlocks2, 256, 0, stream>>>(cnt2, bsum, cur, inv2, n2);
    place_kernel<<<(E + 255) / 256, 256, 0, stream>>>(src, dstp, et, cur, epk, E, N);

    // dtype prep: weights transpose (blocks 0..17) + x cvt (grid-stride)
    const int n4 = (int)(NH / 4);
    cvt_prep_kernel<<<18 + 512, 256, 0, stream>>>(x, xbf, n4, root1, W1, root2, W2, Bt);

    const int Mtiles = (N + 127) / 128;

    // layer 1: fused gather+GEMM -> hbf (relu, bf16)
    gemm_fused<<<Mtiles, 256, 0, stream>>>(xbf, cur, epk, inv2, Bt, b1, nullptr, nullptr,
                                           hbf, nullptr, N, 1);
    // layer 2: fused gather+GEMM + classifier -> out
    gemm_fused<<<Mtiles, 256, 0, stream>>>(hbf, cur, epk, inv2, Bt + (size_t)9 * 16384, b2, Wc, bc,
                                           nullptr, out, N, 2);
}